// Round 5
// baseline (433.336 us; speedup 1.0000x reference)
//
#include <hip/hip_runtime.h>
#include <cstddef>
#include <cstdint>

typedef unsigned short u16;
typedef __attribute__((ext_vector_type(8))) short bf16x8;
typedef __attribute__((ext_vector_type(8))) _Float16 f16x8;
typedef __attribute__((ext_vector_type(4))) float f32x4;
typedef __attribute__((ext_vector_type(16))) float f32x16;

#define GLOBAL_AS __attribute__((address_space(1)))
#define LDS_AS __attribute__((address_space(3)))

__device__ __forceinline__ void async16(const u16* g, u16* l) {
    __builtin_amdgcn_global_load_lds((GLOBAL_AS const uint32_t*)g,
                                     (LDS_AS uint32_t*)l, 16, 0, 0);
}

__device__ __forceinline__ u16 f2bf(float f) {
    uint32_t u = __builtin_bit_cast(uint32_t, f);
    uint32_t r = (u + 0x7FFFu + ((u >> 16) & 1u)) >> 16;
    return (u16)r;
}

// ---------------- elementwise prep ----------------
__global__ __launch_bounds__(256)
void wcast(const float4* __restrict__ src, u16* __restrict__ dst)
{
    int i = blockIdx.x * 256 + threadIdx.x;
    float4 v = src[i];
    ushort4 a = { f2bf(v.x), f2bf(v.y), f2bf(v.z), f2bf(v.w) };
    *(ushort4*)&dst[4 * (size_t)i] = a;
}

// transpose + f16 2-split with x64 scale: fp32 [R,C] -> [C,R] planes h0,h1 of 64*v
__global__ __launch_bounds__(256)
void tsplit_h2(const float* __restrict__ Sb, size_t sBatch,
               u16* __restrict__ Db, size_t dBatch, size_t plane,
               int R, int C)
{
    const float* S = Sb + blockIdx.z * sBatch;
    u16* D = Db + blockIdx.z * dBatch;
    __shared__ float t[32][33];
    int tx = threadIdx.x & 31, ty = threadIdx.x >> 5;
    int c0 = blockIdx.x * 32, r0 = blockIdx.y * 32;
    #pragma unroll
    for (int k = 0; k < 4; ++k)
        t[ty + 8 * k][tx] = S[(size_t)(r0 + ty + 8 * k) * C + c0 + tx];
    __syncthreads();
    #pragma unroll
    for (int k = 0; k < 4; ++k) {
        float a = t[tx][ty + 8 * k] * 64.0f;
        _Float16 h0 = (_Float16)a;
        _Float16 h1 = (_Float16)(a - (float)h0);
        size_t o = (size_t)(c0 + ty + 8 * k) * R + r0 + tx;
        D[o] = __builtin_bit_cast(u16, h0);
        D[plane + o] = __builtin_bit_cast(u16, h1);
    }
}

// fused x-prep: fp32 x [1024, 2048] -> bf16 copy [1024,2048] AND transposed
// f16 2-plane x64 split [2048, 1024]
__global__ __launch_bounds__(256)
void xprep(const float* __restrict__ Sb, size_t sBatch,
           u16* __restrict__ BFb, size_t bfBatch,
           u16* __restrict__ Db, size_t dBatch, size_t plane)
{
    const float* S = Sb + blockIdx.z * sBatch;
    u16* BF = BFb + blockIdx.z * bfBatch;
    u16* D = Db + blockIdx.z * dBatch;
    __shared__ float t[32][33];
    int tx = threadIdx.x & 31, ty = threadIdx.x >> 5;
    int c0 = blockIdx.x * 32, r0 = blockIdx.y * 32;
    #pragma unroll
    for (int k = 0; k < 4; ++k) {
        float v = S[(size_t)(r0 + ty + 8 * k) * 2048 + c0 + tx];
        t[ty + 8 * k][tx] = v;
        BF[(size_t)(r0 + ty + 8 * k) * 2048 + c0 + tx] = f2bf(v);
    }
    __syncthreads();
    #pragma unroll
    for (int k = 0; k < 4; ++k) {
        float a = t[tx][ty + 8 * k] * 64.0f;
        _Float16 h0 = (_Float16)a;
        _Float16 h1 = (_Float16)(a - (float)h0);
        size_t o = (size_t)(c0 + ty + 8 * k) * 1024 + r0 + tx;
        D[o] = __builtin_bit_cast(u16, h0);
        D[plane + o] = __builtin_bit_cast(u16, h1);
    }
}

// transpose + cast: fp32 [R,C] -> bf16 [C,R]
__global__ __launch_bounds__(256)
void tcast(const float* __restrict__ S, u16* __restrict__ D, int R, int C)
{
    __shared__ float t[32][33];
    int tx = threadIdx.x & 31, ty = threadIdx.x >> 5;
    int c0 = blockIdx.x * 32, r0 = blockIdx.y * 32;
    #pragma unroll
    for (int k = 0; k < 4; ++k)
        t[ty + 8 * k][tx] = S[(size_t)(r0 + ty + 8 * k) * C + c0 + tx];
    __syncthreads();
    #pragma unroll
    for (int k = 0; k < 4; ++k)
        D[(size_t)(c0 + ty + 8 * k) * R + r0 + tx] = f2bf(t[tx][ty + 8 * k]);
}

// bf16 [2048,2048] transpose
__global__ __launch_bounds__(256)
void tbf16(const u16* __restrict__ Sb, size_t sBatch, u16* __restrict__ Db, size_t dBatch)
{
    const u16* S = Sb + blockIdx.z * sBatch;
    u16* D = Db + blockIdx.z * dBatch;
    __shared__ u16 t[32][34];
    int tx = threadIdx.x & 31, ty = threadIdx.x >> 5;
    int c0 = blockIdx.x * 32, r0 = blockIdx.y * 32;
    #pragma unroll
    for (int k = 0; k < 4; ++k)
        t[ty + 8 * k][tx] = S[(size_t)(r0 + ty + 8 * k) * 2048 + c0 + tx];
    __syncthreads();
    #pragma unroll
    for (int k = 0; k < 4; ++k)
        D[(size_t)(c0 + ty + 8 * k) * 2048 + r0 + tx] = t[tx][ty + 8 * k];
}

// ---------------- 128-tile 16x16 MFMA GEMM (weight prep only, 256 thr) ----------------
#define MMF4(AF, BF)                                                                   \
    _Pragma("unroll") for (int i = 0; i < 4; ++i)                                      \
        _Pragma("unroll") for (int j = 0; j < 4; ++j)                                  \
            acc[i][j] = __builtin_amdgcn_mfma_f32_16x16x32_f16(AF[i], BF[j], acc[i][j], 0, 0, 0);
#define MMB4(AF, BF)                                                                   \
    _Pragma("unroll") for (int i = 0; i < 4; ++i)                                      \
        _Pragma("unroll") for (int j = 0; j < 4; ++j)                                  \
            acc[i][j] = __builtin_amdgcn_mfma_f32_16x16x32_bf16(AF[i], BF[j], acc[i][j], 0, 0, 0);

template<int TERMS, int EPI>
__global__ __launch_bounds__(256)
void gemm_big(const u16* __restrict__ Ab, size_t aBatch, size_t aPlane,
              const u16* __restrict__ Bb, size_t bBatch, size_t bPlane,
              void* __restrict__ Cb, size_t cBatch, size_t cPlane,
              int M, int N, int K)
{
    constexpr int RSZ = 4096;
    constexpr int BUF = (TERMS == 3 ? 4 : 2) * RSZ;
    __shared__ u16 lds[2 * BUF];
    const u16* A = Ab + blockIdx.z * aBatch;
    const u16* B = Bb + blockIdx.z * bBatch;
    const int tid = threadIdx.x;
    const int lane = tid & 63, wave = tid >> 6;
    const int m0 = blockIdx.y * 128, n0 = blockIdx.x * 128;
    const int l15 = lane & 15, q = lane >> 4;
    const int rm = (wave >> 1) * 64, rn = (wave & 1) * 64;

    int sr[2], sg[2], sbase[2];
    #pragma unroll
    for (int it = 0; it < 2; ++it) {
        int s = tid + it * 256;
        sr[it] = s >> 2;
        sg[it] = (s & 3) ^ ((sr[it] >> 1) & 3);
        sbase[it] = (it * 256 + wave * 64) * 8;
    }
    const int fsw = (q ^ ((l15 >> 1) & 3)) * 8;
    int aoff[4], boff[4];
    #pragma unroll
    for (int f = 0; f < 4; ++f) {
        aoff[f] = (rm + f * 16 + l15) * 32 + fsw;
        boff[f] = (rn + f * 16 + l15) * 32 + fsw;
    }

    f32x4 acc[4][4];
    #pragma unroll
    for (int i = 0; i < 4; ++i)
        #pragma unroll
        for (int j = 0; j < 4; ++j)
            acc[i][j] = (f32x4){0.f, 0.f, 0.f, 0.f};

#define STAGEB(PP, KT)                                                                 \
    do {                                                                               \
        _Pragma("unroll")                                                              \
        for (int it = 0; it < 2; ++it) {                                               \
            const size_t ao = (size_t)(m0 + sr[it]) * K + (KT) + sg[it] * 8;           \
            const size_t bo = (size_t)(n0 + sr[it]) * K + (KT) + sg[it] * 8;           \
            const int d = (PP) * BUF + sbase[it];                                      \
            if (TERMS == 3) {                                                          \
                async16(A + ao, &lds[d]);                                              \
                async16(A + aPlane + ao, &lds[d + RSZ]);                               \
                async16(B + bo, &lds[d + 2 * RSZ]);                                    \
                async16(B + bPlane + bo, &lds[d + 3 * RSZ]);                           \
            } else {                                                                   \
                async16(A + ao, &lds[d]);                                              \
                async16(B + bo, &lds[d + RSZ]);                                        \
            }                                                                          \
        }                                                                              \
    } while (0)

    STAGEB(0, 0);
    for (int kt = 0; kt < K; kt += 32) {
        const int p = (kt >> 5) & 1;
        __syncthreads();
        if (kt + 32 < K) STAGEB(p ^ 1, kt + 32);
        const u16* L = &lds[p * BUF];
        if (TERMS == 3) {
            f16x8 a0f[4], b0f[4], xf[4];
            #pragma unroll
            for (int f = 0; f < 4; ++f) a0f[f] = *(const f16x8*)&L[aoff[f]];
            #pragma unroll
            for (int f = 0; f < 4; ++f) b0f[f] = *(const f16x8*)&L[2 * RSZ + boff[f]];
            MMF4(a0f, b0f);
            #pragma unroll
            for (int f = 0; f < 4; ++f) xf[f] = *(const f16x8*)&L[3 * RSZ + boff[f]];
            MMF4(a0f, xf);
            #pragma unroll
            for (int f = 0; f < 4; ++f) xf[f] = *(const f16x8*)&L[RSZ + aoff[f]];
            MMF4(xf, b0f);
        } else {
            bf16x8 af[4], bf_[4];
            #pragma unroll
            for (int f = 0; f < 4; ++f) af[f] = *(const bf16x8*)&L[aoff[f]];
            #pragma unroll
            for (int f = 0; f < 4; ++f) bf_[f] = *(const bf16x8*)&L[RSZ + boff[f]];
            MMB4(af, bf_);
        }
    }
#undef STAGEB

    #pragma unroll
    for (int i = 0; i < 4; ++i) {
        int row = m0 + rm + i * 16 + q * 4;
        #pragma unroll
        for (int j = 0; j < 4; ++j) {
            int col = n0 + rn + j * 16 + l15;
            #pragma unroll
            for (int r = 0; r < 4; ++r) {
                float v = acc[i][j][r];
                size_t o = (size_t)(row + r) * N + col;
                if (EPI == 0) {
                    ((float*)Cb + blockIdx.z * cBatch)[o] = v;
                } else if (EPI == 1) {
                    u16* C0 = (u16*)Cb + blockIdx.z * cBatch;
                    float vs = v * 0.000244140625f;
                    _Float16 h0 = (_Float16)vs;
                    _Float16 h1 = (_Float16)(vs - (float)h0);
                    C0[o] = __builtin_bit_cast(u16, h0);
                    C0[cPlane + o] = __builtin_bit_cast(u16, h1);
                } else {
                    ((u16*)Cb + blockIdx.z * cBatch)[o] = f2bf(v);
                }
            }
        }
    }
}

// shared fragment-read / MFMA macros for the split GEMMs (layout: A0|A1|B0|B1)
#define RDAF(dst, PL, H)                                                               \
    _Pragma("unroll")                                                                  \
    for (int f = 0; f < FM; ++f)                                                       \
        dst[f] = *(const f16x8*)&L[(PL) * ASZ + arow[f] * 32 + ((2 * (H) + half) ^ asw[f]) * 8];
#define RDBF(dst, PL, H)                                                               \
    _Pragma("unroll")                                                                  \
    for (int f = 0; f < FN; ++f)                                                       \
        dst[f] = *(const f16x8*)&L[2 * ASZ + (PL) * BSZ + brow[f] * 32 + ((2 * (H) + half) ^ bsw[f]) * 8];
#define MMW(AF, BF)                                                                    \
    _Pragma("unroll")                                                                  \
    for (int i = 0; i < FM; ++i)                                                       \
        _Pragma("unroll")                                                              \
        for (int j = 0; j < FN; ++j)                                                   \
            acc[i][j] = __builtin_amdgcn_mfma_f32_32x32x16_f16(AF[i], BF[j], acc[i][j], 0, 0, 0);
#define MMWB(AF, BF)                                                                   \
    _Pragma("unroll")                                                                  \
    for (int i = 0; i < FM; ++i)                                                       \
        _Pragma("unroll")                                                              \
        for (int j = 0; j < FN; ++j)                                                   \
            acc[i][j] = __builtin_amdgcn_mfma_f32_32x32x16_bf16(AF[i], BF[j], acc[i][j], 0, 0, 0);

// ---------------- wide-tile 32x32x16 bf16 GEMM (512 thr, dyn LDS, dbuf) ----------------
// Used for XPT / out gemms (TERMS=1 only now). EPI: 0 fp32, 2 bf16.
template<int TERMS, int EPI, int TM, int TN, int WGM, int WGN>
__global__ __launch_bounds__(512, 2)
void gemm_w(const u16* __restrict__ Ab, size_t aBatch, size_t aPlane,
            const u16* __restrict__ Bb, size_t bBatch, size_t bPlane,
            void* __restrict__ Cb, size_t cBatch, size_t cPlane,
            int M, int N, int K)
{
    constexpr int ASZ = TM * 32;
    constexpr int BSZ = TN * 32;
    constexpr int APL = (TERMS == 3) ? 2 : 1;
    constexpr int BUF = APL * (ASZ + BSZ);
    constexpr int FM = TM / WGM / 32;
    constexpr int FN = TN / WGN / 32;
    constexpr int AIT = TM / 128;
    constexpr int BIT = TN / 128;
    extern __shared__ __align__(16) u16 lds[];

    int bid = blockIdx.x + gridDim.x * blockIdx.y;
    int cpr = gridDim.x >> 2;
    int c8 = bid & 7, kk = bid >> 3;
    int bx = (kk % cpr) * 4 + (c8 & 3);
    int by = (kk / cpr) * 2 + (c8 >> 2);

    const u16* A = Ab + blockIdx.z * aBatch;
    const u16* B = Bb + blockIdx.z * bBatch;
    const int tid = threadIdx.x;
    const int lane = tid & 63, wave = tid >> 6;
    const int m0 = by * TM, n0 = bx * TN;
    const int l31 = lane & 31, half = lane >> 5;
    const int rm = (wave / WGN) * (TM / WGM);
    const int rn = (wave % WGN) * (TN / WGN);

    int arow[FM], asw[FM], brow[FN], bsw[FN];
    #pragma unroll
    for (int f = 0; f < FM; ++f) { arow[f] = rm + f * 32 + l31; asw[f] = (arow[f] >> 1) & 3; }
    #pragma unroll
    for (int f = 0; f < FN; ++f) { brow[f] = rn + f * 32 + l31; bsw[f] = (brow[f] >> 1) & 3; }

    f32x16 acc[FM][FN];
    #pragma unroll
    for (int i = 0; i < FM; ++i)
        #pragma unroll
        for (int j = 0; j < FN; ++j)
            #pragma unroll
            for (int r = 0; r < 16; ++r) acc[i][j][r] = 0.f;

    auto stage = [&](int pp, int kt) {
        #pragma unroll
        for (int it = 0; it < AIT; ++it) {
            int s = tid + it * 512;
            int r = s >> 2;
            int g = (s & 3) ^ ((r >> 1) & 3);
            int base = pp * BUF + (it * 512 + wave * 64) * 8;
            size_t go = (size_t)(m0 + r) * K + kt + g * 8;
            async16(A + go, &lds[base]);
            if (TERMS == 3) async16(A + aPlane + go, &lds[base + ASZ]);
        }
        #pragma unroll
        for (int it = 0; it < BIT; ++it) {
            int s = tid + it * 512;
            int r = s >> 2;
            int g = (s & 3) ^ ((r >> 1) & 3);
            int base = pp * BUF + APL * ASZ + (it * 512 + wave * 64) * 8;
            size_t go = (size_t)(n0 + r) * K + kt + g * 8;
            async16(B + go, &lds[base]);
            if (TERMS == 3) async16(B + bPlane + go, &lds[base + BSZ]);
        }
    };

    stage(0, 0);
    for (int kt = 0; kt < K; kt += 32) {
        const int p = (kt >> 5) & 1;
        __syncthreads();
        if (kt + 32 < K) stage(p ^ 1, kt + 32);
        const u16* L = &lds[p * BUF];
        bf16x8 Ah0[FM], Ah1[FM], Bh0[FN], Bh1[FN];
        #pragma unroll
        for (int f = 0; f < FM; ++f)
            Ah0[f] = *(const bf16x8*)&L[arow[f] * 32 + (half ^ asw[f]) * 8];
        #pragma unroll
        for (int f = 0; f < FN; ++f)
            Bh0[f] = *(const bf16x8*)&L[ASZ + brow[f] * 32 + (half ^ bsw[f]) * 8];
        #pragma unroll
        for (int f = 0; f < FM; ++f)
            Ah1[f] = *(const bf16x8*)&L[arow[f] * 32 + ((2 + half) ^ asw[f]) * 8];
        #pragma unroll
        for (int f = 0; f < FN; ++f)
            Bh1[f] = *(const bf16x8*)&L[ASZ + brow[f] * 32 + ((2 + half) ^ bsw[f]) * 8];
        MMWB(Ah0, Bh0)
        MMWB(Ah1, Bh1)
    }

    #pragma unroll
    for (int i = 0; i < FM; ++i) {
        #pragma unroll
        for (int j = 0; j < FN; ++j) {
            int col = n0 + rn + j * 32 + l31;
            #pragma unroll
            for (int r = 0; r < 16; ++r) {
                int row = m0 + rm + i * 32 + (r & 3) + 8 * (r >> 2) + 4 * half;
                float v = acc[i][j][r];
                size_t o = (size_t)row * N + col;
                if (EPI == 0) {
                    ((float*)Cb + blockIdx.z * cBatch)[o] = v;
                } else if (EPI == 1) {
                    u16* C0 = (u16*)Cb + blockIdx.z * cBatch;
                    float vs = v * 0.000244140625f;
                    _Float16 h0 = (_Float16)vs;
                    _Float16 h1 = (_Float16)(vs - (float)h0);
                    C0[o] = __builtin_bit_cast(u16, h0);
                    C0[cPlane + o] = __builtin_bit_cast(u16, h1);
                } else {
                    ((u16*)Cb + blockIdx.z * cBatch)[o] = f2bf(v);
                }
            }
        }
    }
}

// ---------------- 3-term f16-split GEMM, 128x128 tile, 2 blocks/CU ----------------
// acc = a0*b0 + a0*b1 + a1*b0. ALL FOUR planes (a0,a1,b0,b1) staged via
// global_load_lds (fully coalesced — fixes R2's strided a1 gather). LDS:
// 4 planes x 128x32 u16 = 32 KB/buf, dbuf 64 KB -> 2 independent blocks/CU
// (launch_bounds(256,2)): one block's barrier/vmcnt stall hides under the
// other block's MFMA (m114 mechanism). 4 waves, each 64x64 (FM=FN=2).
// Inner loop keeps R4's register-pipelined read order (distinct arrays).
template<int EPI>
__global__ __launch_bounds__(256, 2)
void gemm_s4(const u16* __restrict__ Ab, size_t aBatch, size_t aPlane,
             const u16* __restrict__ Bb, size_t bBatch, size_t bPlane,
             void* __restrict__ Cb, size_t cBatch, size_t cPlane,
             int M, int N, int K)
{
    constexpr int TM = 128, TN = 128;
    constexpr int ASZ = TM * 32;
    constexpr int BSZ = TN * 32;
    constexpr int BUF = 2 * (ASZ + BSZ);   // a0|a1|b0|b1 = 16384 el = 32 KB
    constexpr int FM = 2, FN = 2;
    __shared__ u16 lds[2 * BUF];           // 64 KB

    // XCD cluster swizzle (needs gridDim.x%4==0, gridDim.y%2==0)
    int bid = blockIdx.x + gridDim.x * blockIdx.y;
    int cpr = gridDim.x >> 2;
    int c8 = bid & 7, kk = bid >> 3;
    int bx = (kk % cpr) * 4 + (c8 & 3);
    int by = (kk / cpr) * 2 + (c8 >> 2);

    const u16* A = Ab + blockIdx.z * aBatch;
    const u16* B = Bb + blockIdx.z * bBatch;
    const int tid = threadIdx.x;
    const int lane = tid & 63, wave = tid >> 6;
    const int m0 = by * TM, n0 = bx * TN;
    const int l31 = lane & 31, half = lane >> 5;
    const int rm = (wave >> 1) * 64;       // WGM=2
    const int rn = (wave & 1) * 64;        // WGN=2

    int arow[FM], asw[FM], brow[FN], bsw[FN];
    #pragma unroll
    for (int f = 0; f < FM; ++f) { arow[f] = rm + f * 32 + l31; asw[f] = (arow[f] >> 1) & 3; }
    #pragma unroll
    for (int f = 0; f < FN; ++f) { brow[f] = rn + f * 32 + l31; bsw[f] = (brow[f] >> 1) & 3; }

    f32x16 acc[FM][FN];
    #pragma unroll
    for (int i = 0; i < FM; ++i)
        #pragma unroll
        for (int j = 0; j < FN; ++j)
            #pragma unroll
            for (int r = 0; r < 16; ++r) acc[i][j][r] = 0.f;

    auto stage = [&](int pp, int kt) {
        #pragma unroll
        for (int it = 0; it < 2; ++it) {
            int s = tid + it * 256;
            int r = s >> 2;
            int g = (s & 3) ^ ((r >> 1) & 3);
            int base = pp * BUF + (it * 256 + wave * 64) * 8;
            size_t go = (size_t)(m0 + r) * K + kt + g * 8;
            async16(A + go, &lds[base]);
            async16(A + aPlane + go, &lds[base + ASZ]);
        }
        #pragma unroll
        for (int it = 0; it < 2; ++it) {
            int s = tid + it * 256;
            int r = s >> 2;
            int g = (s & 3) ^ ((r >> 1) & 3);
            int base = pp * BUF + 2 * ASZ + (it * 256 + wave * 64) * 8;
            size_t go = (size_t)(n0 + r) * K + kt + g * 8;
            async16(B + go, &lds[base]);
            async16(B + bPlane + go, &lds[base + BSZ]);
        }
    };

    stage(0, 0);
    for (int kt = 0; kt < K; kt += 32) {
        const int p = (kt >> 5) & 1;
        __syncthreads();
        if (kt + 32 < K) stage(p ^ 1, kt + 32);
        const u16* L = &lds[p * BUF];
        // pipelined: reads for group g+1 before MFMAs of group g, no array reuse
        f16x8 A0h0[FM], A0h1[FM], B0h0[FN], B0h1[FN];
        f16x8 B1h0[FN], B1h1[FN], A1h0[FM], A1h1[FM];
        RDAF(A0h0, 0, 0) RDBF(B0h0, 0, 0)
        RDAF(A0h1, 0, 1) RDBF(B0h1, 0, 1)
        RDBF(B1h0, 1, 0)
        MMW(A0h0, B0h0)
        RDBF(B1h1, 1, 1)
        MMW(A0h1, B0h1)
        RDAF(A1h0, 1, 0)
        MMW(A0h0, B1h0)
        MMW(A0h1, B1h1)
        RDAF(A1h1, 1, 1)
        MMW(A1h0, B0h0)
        MMW(A1h1, B0h1)
    }

    #pragma unroll
    for (int i = 0; i < FM; ++i) {
        #pragma unroll
        for (int j = 0; j < FN; ++j) {
            int col = n0 + rn + j * 32 + l31;
            #pragma unroll
            for (int r = 0; r < 16; ++r) {
                int row = m0 + rm + i * 32 + (r & 3) + 8 * (r >> 2) + 4 * half;
                float v = acc[i][j][r];
                size_t o = (size_t)row * N + col;
                if (EPI == 0) {
                    ((float*)Cb + blockIdx.z * cBatch)[o] = v;
                } else if (EPI == 1) {
                    u16* C0 = (u16*)Cb + blockIdx.z * cBatch;
                    float vs = v * 0.000244140625f;
                    _Float16 h0 = (_Float16)vs;
                    _Float16 h1 = (_Float16)(vs - (float)h0);
                    C0[o] = __builtin_bit_cast(u16, h0);
                    C0[cPlane + o] = __builtin_bit_cast(u16, h1);
                } else {
                    ((u16*)Cb + blockIdx.z * cBatch)[o] = f2bf(v);
                }
            }
        }
    }
}

#undef RDAF
#undef RDBF
#undef MMW
#undef MMWB

// ---------------- row softmax (2048 cols) -> bf16 ----------------
__global__ __launch_bounds__(256)
void softmax_p(const float* __restrict__ Sb, size_t sBatch, u16* __restrict__ Pb, size_t pBatch)
{
    const float* S = Sb + blockIdx.y * sBatch + (size_t)blockIdx.x * 2048;
    u16* P = Pb + blockIdx.y * pBatch + (size_t)blockIdx.x * 2048;
    const int tid = threadIdx.x;

    float4 v0 = *(const float4*)&S[tid * 4];
    float4 v1 = *(const float4*)&S[1024 + tid * 4];

    float m = fmaxf(fmaxf(fmaxf(v0.x, v0.y), fmaxf(v0.z, v0.w)),
                    fmaxf(fmaxf(v1.x, v1.y), fmaxf(v1.z, v1.w)));
    #pragma unroll
    for (int off = 32; off > 0; off >>= 1)
        m = fmaxf(m, __shfl_xor(m, off, 64));
    __shared__ float redm[4];
    if ((tid & 63) == 0) redm[tid >> 6] = m;
    __syncthreads();
    m = fmaxf(fmaxf(redm[0], redm[1]), fmaxf(redm[2], redm[3]));

    v0.x = __expf(v0.x - m); v0.y = __expf(v0.y - m);
    v0.z = __expf(v0.z - m); v0.w = __expf(v0.w - m);
    v1.x = __expf(v1.x - m); v1.y = __expf(v1.y - m);
    v1.z = __expf(v1.z - m); v1.w = __expf(v1.w - m);

    float s = v0.x + v0.y + v0.z + v0.w + v1.x + v1.y + v1.z + v1.w;
    #pragma unroll
    for (int off = 32; off > 0; off >>= 1)
        s += __shfl_xor(s, off, 64);
    __shared__ float reds[4];
    if ((tid & 63) == 0) reds[tid >> 6] = s;
    __syncthreads();
    s = reds[0] + reds[1] + reds[2] + reds[3];

    const float r = 1.0f / s;
    ushort4 o0 = { f2bf(v0.x * r), f2bf(v0.y * r), f2bf(v0.z * r), f2bf(v0.w * r) };
    ushort4 o1 = { f2bf(v1.x * r), f2bf(v1.y * r), f2bf(v1.z * r), f2bf(v1.w * r) };
    *(ushort4*)&P[tid * 4] = o0;
    *(ushort4*)&P[1024 + tid * 4] = o1;
}

// ---------------- driver ----------------
extern "C" void kernel_launch(void* const* d_in, const int* in_sizes, int n_in,
                              void* d_out, int out_size, void* d_ws, size_t ws_size,
                              hipStream_t stream)
{
    const size_t MB = 1048576;
    const size_t WREG = 34 * MB;
    const size_t PER  = 32 * MB;
    const size_t PER_US = PER / 2, PER_F = PER / 4;

    char* ws = (char*)d_ws;
    u16* WQT2 = (u16*)ws;
    u16* WKT2 = (u16*)(ws + 4 * MB);
    u16* M2   = (u16*)(ws + 8 * MB);
    u16* WObf = (u16*)(ws + 12 * MB);
    u16* WVT  = (u16*)(ws + 14 * MB);
    u16* WOV  = (u16*)(ws + 16 * MB);
    u16* xbf  = (u16*)(ws + 18 * MB);

    int G = (ws_size >= WREG + 4 * PER) ? 4 : (ws_size >= WREG + 2 * PER) ? 2 : 1;

    const float* x = (const float*)d_in[0];
    float* out = (float*)d_out;
    dim3 blk(256);

    // ---- weight prep (once) ----
    tsplit_h2<<<dim3(32, 32, 1), blk, 0, stream>>>((const float*)d_in[1], 0, WQT2, 0, 1048576, 1024, 1024);
    tsplit_h2<<<dim3(32, 32, 1), blk, 0, stream>>>((const float*)d_in[2], 0, WKT2, 0, 1048576, 1024, 1024);
    gemm_big<3, 1><<<dim3(8, 8, 1), blk, 0, stream>>>(WKT2, 0, 1048576, WQT2, 0, 1048576,
                                                      M2, 0, 1048576, 1024, 1024, 1024);
    wcast<<<1024, blk, 0, stream>>>((const float4*)d_in[4], WObf);
    tcast<<<dim3(32, 32, 1), blk, 0, stream>>>((const float*)d_in[3], WVT, 1024, 1024);
    gemm_big<1, 2><<<dim3(8, 8, 1), blk, 0, stream>>>(WObf, 0, 0, WVT, 0, 0,
                                                      WOV, 0, 0, 1024, 1024, 1024);

    for (int b0 = 0; b0 < 4; b0 += G) {
        char* R = ws + WREG;
        u16*   xT2 = (u16*)R;               // [i,d] 64x f16-split, plane 2097152 u16
        u16*   TT2 = (u16*)(R + 8 * MB);    // [j,d] split(T/64)
        float* S32 = (float*)(R + 16 * MB); // fp32 [i,j]
        u16*   Pb  = (u16*)R;               // bf16 [i,j] (over dead xT2)
        u16*   PTb = (u16*)(R + 8 * MB);    // bf16 [j,i] (over dead TT2)
        u16*   XPT = (u16*)(R + 16 * MB);   // bf16 [j,d'] (over dead S32)

        // x -> xbf (bf16 copy) + xT2 (transposed 64x f16 2-plane), one pass
        xprep<<<dim3(64, 32, G), blk, 0, stream>>>(x + (size_t)b0 * 2097152, 2097152,
                                                   xbf + (size_t)b0 * 2097152, 2097152,
                                                   xT2, PER_US, 2097152);
        // T^T = (64x)^T M: [j,d] f16-split out  (M=2048,N=1024 -> grid 8x16)
        gemm_s4<1><<<dim3(8, 16, G), blk, 0, stream>>>(
            xT2, PER_US, 2097152, M2, 0, 1048576, TT2, PER_US, 2097152, 2048, 1024, 1024);
        // S[i,j] = (64x)[i,:] . (T/64)[j,:]  (M=N=2048 -> grid 16x16)
        gemm_s4<0><<<dim3(16, 16, G), blk, 0, stream>>>(
            xT2, PER_US, 2097152, TT2, PER_US, 2097152, S32, PER_F, 0, 2048, 2048, 1024);
        softmax_p<<<dim3(2048, G), blk, 0, stream>>>(S32, PER_F, Pb, PER_US);
        tbf16<<<dim3(64, 64, G), blk, 0, stream>>>(Pb, PER_US, PTb, PER_US);
        // XPT[j,d'] = PT[j,:] . xbf[d',:]
        gemm_w<1, 2, 256, 128, 4, 2><<<dim3(8, 8, G), 512, 49152, stream>>>(
            PTb, PER_US, 0, xbf + (size_t)b0 * 2097152, 2097152, 0,
            XPT, PER_US, 0, 2048, 1024, 2048);
        // out[d,j] = WOV[d,:] . XPT[j,:]
        gemm_w<1, 0, 256, 128, 4, 2><<<dim3(16, 4, G), 512, 49152, stream>>>(
            WOV, 0, 0, XPT, PER_US, 0, out + (size_t)b0 * 2097152, 2097152, 0,
            1024, 2048, 1024);
    }
}

// Round 6
// 412.460 us; speedup vs baseline: 1.0506x; 1.0506x over previous
//
#include <hip/hip_runtime.h>
#include <cstddef>
#include <cstdint>

typedef unsigned short u16;
typedef __attribute__((ext_vector_type(8))) short bf16x8;
typedef __attribute__((ext_vector_type(8))) _Float16 f16x8;
typedef __attribute__((ext_vector_type(4))) float f32x4;
typedef __attribute__((ext_vector_type(16))) float f32x16;

#define GLOBAL_AS __attribute__((address_space(1)))
#define LDS_AS __attribute__((address_space(3)))

__device__ __forceinline__ void async16(const u16* g, u16* l) {
    __builtin_amdgcn_global_load_lds((GLOBAL_AS const uint32_t*)g,
                                     (LDS_AS uint32_t*)l, 16, 0, 0);
}

__device__ __forceinline__ u16 f2bf(float f) {
    uint32_t u = __builtin_bit_cast(uint32_t, f);
    uint32_t r = (u + 0x7FFFu + ((u >> 16) & 1u)) >> 16;
    return (u16)r;
}

// ---------------- elementwise prep ----------------
__global__ __launch_bounds__(256)
void wcast(const float4* __restrict__ src, u16* __restrict__ dst)
{
    int i = blockIdx.x * 256 + threadIdx.x;
    float4 v = src[i];
    ushort4 a = { f2bf(v.x), f2bf(v.y), f2bf(v.z), f2bf(v.w) };
    *(ushort4*)&dst[4 * (size_t)i] = a;
}

// transpose + f16 2-split with x64 scale: fp32 [R,C] -> [C,R] planes h0,h1 of 64*v
__global__ __launch_bounds__(256)
void tsplit_h2(const float* __restrict__ Sb, size_t sBatch,
               u16* __restrict__ Db, size_t dBatch, size_t plane,
               int R, int C)
{
    const float* S = Sb + blockIdx.z * sBatch;
    u16* D = Db + blockIdx.z * dBatch;
    __shared__ float t[32][33];
    int tx = threadIdx.x & 31, ty = threadIdx.x >> 5;
    int c0 = blockIdx.x * 32, r0 = blockIdx.y * 32;
    #pragma unroll
    for (int k = 0; k < 4; ++k)
        t[ty + 8 * k][tx] = S[(size_t)(r0 + ty + 8 * k) * C + c0 + tx];
    __syncthreads();
    #pragma unroll
    for (int k = 0; k < 4; ++k) {
        float a = t[tx][ty + 8 * k] * 64.0f;
        _Float16 h0 = (_Float16)a;
        _Float16 h1 = (_Float16)(a - (float)h0);
        size_t o = (size_t)(c0 + ty + 8 * k) * R + r0 + tx;
        D[o] = __builtin_bit_cast(u16, h0);
        D[plane + o] = __builtin_bit_cast(u16, h1);
    }
}

// fused x-prep: fp32 x [1024, 2048] -> bf16 copy [1024,2048] AND transposed
// f16 2-plane x64 split [2048, 1024]
__global__ __launch_bounds__(256)
void xprep(const float* __restrict__ Sb, size_t sBatch,
           u16* __restrict__ BFb, size_t bfBatch,
           u16* __restrict__ Db, size_t dBatch, size_t plane)
{
    const float* S = Sb + blockIdx.z * sBatch;
    u16* BF = BFb + blockIdx.z * bfBatch;
    u16* D = Db + blockIdx.z * dBatch;
    __shared__ float t[32][33];
    int tx = threadIdx.x & 31, ty = threadIdx.x >> 5;
    int c0 = blockIdx.x * 32, r0 = blockIdx.y * 32;
    #pragma unroll
    for (int k = 0; k < 4; ++k) {
        float v = S[(size_t)(r0 + ty + 8 * k) * 2048 + c0 + tx];
        t[ty + 8 * k][tx] = v;
        BF[(size_t)(r0 + ty + 8 * k) * 2048 + c0 + tx] = f2bf(v);
    }
    __syncthreads();
    #pragma unroll
    for (int k = 0; k < 4; ++k) {
        float a = t[tx][ty + 8 * k] * 64.0f;
        _Float16 h0 = (_Float16)a;
        _Float16 h1 = (_Float16)(a - (float)h0);
        size_t o = (size_t)(c0 + ty + 8 * k) * 1024 + r0 + tx;
        D[o] = __builtin_bit_cast(u16, h0);
        D[plane + o] = __builtin_bit_cast(u16, h1);
    }
}

// transpose + cast: fp32 [R,C] -> bf16 [C,R]
__global__ __launch_bounds__(256)
void tcast(const float* __restrict__ S, u16* __restrict__ D, int R, int C)
{
    __shared__ float t[32][33];
    int tx = threadIdx.x & 31, ty = threadIdx.x >> 5;
    int c0 = blockIdx.x * 32, r0 = blockIdx.y * 32;
    #pragma unroll
    for (int k = 0; k < 4; ++k)
        t[ty + 8 * k][tx] = S[(size_t)(r0 + ty + 8 * k) * C + c0 + tx];
    __syncthreads();
    #pragma unroll
    for (int k = 0; k < 4; ++k)
        D[(size_t)(c0 + ty + 8 * k) * R + r0 + tx] = f2bf(t[tx][ty + 8 * k]);
}

// bf16 [2048,2048] transpose
__global__ __launch_bounds__(256)
void tbf16(const u16* __restrict__ Sb, size_t sBatch, u16* __restrict__ Db, size_t dBatch)
{
    const u16* S = Sb + blockIdx.z * sBatch;
    u16* D = Db + blockIdx.z * dBatch;
    __shared__ u16 t[32][34];
    int tx = threadIdx.x & 31, ty = threadIdx.x >> 5;
    int c0 = blockIdx.x * 32, r0 = blockIdx.y * 32;
    #pragma unroll
    for (int k = 0; k < 4; ++k)
        t[ty + 8 * k][tx] = S[(size_t)(r0 + ty + 8 * k) * 2048 + c0 + tx];
    __syncthreads();
    #pragma unroll
    for (int k = 0; k < 4; ++k)
        D[(size_t)(c0 + ty + 8 * k) * 2048 + r0 + tx] = t[tx][ty + 8 * k];
}

// ---------------- 128-tile 16x16 MFMA GEMM (weight prep only, 256 thr) ----------------
#define MMF4(AF, BF)                                                                   \
    _Pragma("unroll") for (int i = 0; i < 4; ++i)                                      \
        _Pragma("unroll") for (int j = 0; j < 4; ++j)                                  \
            acc[i][j] = __builtin_amdgcn_mfma_f32_16x16x32_f16(AF[i], BF[j], acc[i][j], 0, 0, 0);
#define MMB4(AF, BF)                                                                   \
    _Pragma("unroll") for (int i = 0; i < 4; ++i)                                      \
        _Pragma("unroll") for (int j = 0; j < 4; ++j)                                  \
            acc[i][j] = __builtin_amdgcn_mfma_f32_16x16x32_bf16(AF[i], BF[j], acc[i][j], 0, 0, 0);

template<int TERMS, int EPI>
__global__ __launch_bounds__(256)
void gemm_big(const u16* __restrict__ Ab, size_t aBatch, size_t aPlane,
              const u16* __restrict__ Bb, size_t bBatch, size_t bPlane,
              void* __restrict__ Cb, size_t cBatch, size_t cPlane,
              int M, int N, int K)
{
    constexpr int RSZ = 4096;
    constexpr int BUF = (TERMS == 3 ? 4 : 2) * RSZ;
    __shared__ u16 lds[2 * BUF];
    const u16* A = Ab + blockIdx.z * aBatch;
    const u16* B = Bb + blockIdx.z * bBatch;
    const int tid = threadIdx.x;
    const int lane = tid & 63, wave = tid >> 6;
    const int m0 = blockIdx.y * 128, n0 = blockIdx.x * 128;
    const int l15 = lane & 15, q = lane >> 4;
    const int rm = (wave >> 1) * 64, rn = (wave & 1) * 64;

    int sr[2], sg[2], sbase[2];
    #pragma unroll
    for (int it = 0; it < 2; ++it) {
        int s = tid + it * 256;
        sr[it] = s >> 2;
        sg[it] = (s & 3) ^ ((sr[it] >> 1) & 3);
        sbase[it] = (it * 256 + wave * 64) * 8;
    }
    const int fsw = (q ^ ((l15 >> 1) & 3)) * 8;
    int aoff[4], boff[4];
    #pragma unroll
    for (int f = 0; f < 4; ++f) {
        aoff[f] = (rm + f * 16 + l15) * 32 + fsw;
        boff[f] = (rn + f * 16 + l15) * 32 + fsw;
    }

    f32x4 acc[4][4];
    #pragma unroll
    for (int i = 0; i < 4; ++i)
        #pragma unroll
        for (int j = 0; j < 4; ++j)
            acc[i][j] = (f32x4){0.f, 0.f, 0.f, 0.f};

#define STAGEB(PP, KT)                                                                 \
    do {                                                                               \
        _Pragma("unroll")                                                              \
        for (int it = 0; it < 2; ++it) {                                               \
            const size_t ao = (size_t)(m0 + sr[it]) * K + (KT) + sg[it] * 8;           \
            const size_t bo = (size_t)(n0 + sr[it]) * K + (KT) + sg[it] * 8;           \
            const int d = (PP) * BUF + sbase[it];                                      \
            if (TERMS == 3) {                                                          \
                async16(A + ao, &lds[d]);                                              \
                async16(A + aPlane + ao, &lds[d + RSZ]);                               \
                async16(B + bo, &lds[d + 2 * RSZ]);                                    \
                async16(B + bPlane + bo, &lds[d + 3 * RSZ]);                           \
            } else {                                                                   \
                async16(A + ao, &lds[d]);                                              \
                async16(B + bo, &lds[d + RSZ]);                                        \
            }                                                                          \
        }                                                                              \
    } while (0)

    STAGEB(0, 0);
    for (int kt = 0; kt < K; kt += 32) {
        const int p = (kt >> 5) & 1;
        __syncthreads();
        if (kt + 32 < K) STAGEB(p ^ 1, kt + 32);
        const u16* L = &lds[p * BUF];
        if (TERMS == 3) {
            f16x8 a0f[4], b0f[4], xf[4];
            #pragma unroll
            for (int f = 0; f < 4; ++f) a0f[f] = *(const f16x8*)&L[aoff[f]];
            #pragma unroll
            for (int f = 0; f < 4; ++f) b0f[f] = *(const f16x8*)&L[2 * RSZ + boff[f]];
            MMF4(a0f, b0f);
            #pragma unroll
            for (int f = 0; f < 4; ++f) xf[f] = *(const f16x8*)&L[3 * RSZ + boff[f]];
            MMF4(a0f, xf);
            #pragma unroll
            for (int f = 0; f < 4; ++f) xf[f] = *(const f16x8*)&L[RSZ + aoff[f]];
            MMF4(xf, b0f);
        } else {
            bf16x8 af[4], bf_[4];
            #pragma unroll
            for (int f = 0; f < 4; ++f) af[f] = *(const bf16x8*)&L[aoff[f]];
            #pragma unroll
            for (int f = 0; f < 4; ++f) bf_[f] = *(const bf16x8*)&L[RSZ + boff[f]];
            MMB4(af, bf_);
        }
    }
#undef STAGEB

    #pragma unroll
    for (int i = 0; i < 4; ++i) {
        int row = m0 + rm + i * 16 + q * 4;
        #pragma unroll
        for (int j = 0; j < 4; ++j) {
            int col = n0 + rn + j * 16 + l15;
            #pragma unroll
            for (int r = 0; r < 4; ++r) {
                float v = acc[i][j][r];
                size_t o = (size_t)(row + r) * N + col;
                if (EPI == 0) {
                    ((float*)Cb + blockIdx.z * cBatch)[o] = v;
                } else if (EPI == 1) {
                    u16* C0 = (u16*)Cb + blockIdx.z * cBatch;
                    float vs = v * 0.000244140625f;
                    _Float16 h0 = (_Float16)vs;
                    _Float16 h1 = (_Float16)(vs - (float)h0);
                    C0[o] = __builtin_bit_cast(u16, h0);
                    C0[cPlane + o] = __builtin_bit_cast(u16, h1);
                } else {
                    ((u16*)Cb + blockIdx.z * cBatch)[o] = f2bf(v);
                }
            }
        }
    }
}

// shared fragment-read / MFMA macros for the split GEMMs (LDS layout: A0|A1|B0|B1)
#define RDAF(dst, PL, H)                                                               \
    _Pragma("unroll")                                                                  \
    for (int f = 0; f < FM; ++f)                                                       \
        dst[f] = *(const f16x8*)&L[(PL) * ASZ + arow[f] * 32 + ((2 * (H) + half) ^ asw[f]) * 8];
#define RDBF(dst, PL, H)                                                               \
    _Pragma("unroll")                                                                  \
    for (int f = 0; f < FN; ++f)                                                       \
        dst[f] = *(const f16x8*)&L[2 * ASZ + (PL) * BSZ + brow[f] * 32 + ((2 * (H) + half) ^ bsw[f]) * 8];
#define MMW(AF, BF)                                                                    \
    _Pragma("unroll")                                                                  \
    for (int i = 0; i < FM; ++i)                                                       \
        _Pragma("unroll")                                                              \
        for (int j = 0; j < FN; ++j)                                                   \
            acc[i][j] = __builtin_amdgcn_mfma_f32_32x32x16_f16(AF[i], BF[j], acc[i][j], 0, 0, 0);
#define MMWB(AF, BF)                                                                   \
    _Pragma("unroll")                                                                  \
    for (int i = 0; i < FM; ++i)                                                       \
        _Pragma("unroll")                                                              \
        for (int j = 0; j < FN; ++j)                                                   \
            acc[i][j] = __builtin_amdgcn_mfma_f32_32x32x16_bf16(AF[i], BF[j], acc[i][j], 0, 0, 0);

// ---------------- wide-tile 32x32x16 MFMA GEMM (512 thr, dyn LDS, dbuf) ----------------
// TERMS=3: f16 2-plane split, 3 terms (register-pipelined). TERMS=1: bf16.
// EPI: 0 fp32, 1 f16-2split*2^-12, 2 bf16.
template<int TERMS, int EPI, int TM, int TN, int WGM, int WGN>
__global__ __launch_bounds__(512, 2)
void gemm_w(const u16* __restrict__ Ab, size_t aBatch, size_t aPlane,
            const u16* __restrict__ Bb, size_t bBatch, size_t bPlane,
            void* __restrict__ Cb, size_t cBatch, size_t cPlane,
            int M, int N, int K)
{
    constexpr int ASZ = TM * 32;
    constexpr int BSZ = TN * 32;
    constexpr int APL = (TERMS == 3) ? 2 : 1;
    constexpr int BUF = APL * (ASZ + BSZ);
    constexpr int FM = TM / WGM / 32;
    constexpr int FN = TN / WGN / 32;
    constexpr int AIT = TM / 128;
    constexpr int BIT = TN / 128;
    extern __shared__ __align__(16) u16 lds[];

    int bid = blockIdx.x + gridDim.x * blockIdx.y;
    int cpr = gridDim.x >> 2;
    int c8 = bid & 7, kk = bid >> 3;
    int bx = (kk % cpr) * 4 + (c8 & 3);
    int by = (kk / cpr) * 2 + (c8 >> 2);

    const u16* A = Ab + blockIdx.z * aBatch;
    const u16* B = Bb + blockIdx.z * bBatch;
    const int tid = threadIdx.x;
    const int lane = tid & 63, wave = tid >> 6;
    const int m0 = by * TM, n0 = bx * TN;
    const int l31 = lane & 31, half = lane >> 5;
    const int rm = (wave / WGN) * (TM / WGM);
    const int rn = (wave % WGN) * (TN / WGN);

    int arow[FM], asw[FM], brow[FN], bsw[FN];
    #pragma unroll
    for (int f = 0; f < FM; ++f) { arow[f] = rm + f * 32 + l31; asw[f] = (arow[f] >> 1) & 3; }
    #pragma unroll
    for (int f = 0; f < FN; ++f) { brow[f] = rn + f * 32 + l31; bsw[f] = (brow[f] >> 1) & 3; }

    f32x16 acc[FM][FN];
    #pragma unroll
    for (int i = 0; i < FM; ++i)
        #pragma unroll
        for (int j = 0; j < FN; ++j)
            #pragma unroll
            for (int r = 0; r < 16; ++r) acc[i][j][r] = 0.f;

    auto stage = [&](int pp, int kt) {
        #pragma unroll
        for (int it = 0; it < AIT; ++it) {
            int s = tid + it * 512;
            int r = s >> 2;
            int g = (s & 3) ^ ((r >> 1) & 3);
            int base = pp * BUF + (it * 512 + wave * 64) * 8;
            size_t go = (size_t)(m0 + r) * K + kt + g * 8;
            async16(A + go, &lds[base]);
            if (TERMS == 3) async16(A + aPlane + go, &lds[base + ASZ]);
        }
        #pragma unroll
        for (int it = 0; it < BIT; ++it) {
            int s = tid + it * 512;
            int r = s >> 2;
            int g = (s & 3) ^ ((r >> 1) & 3);
            int base = pp * BUF + APL * ASZ + (it * 512 + wave * 64) * 8;
            size_t go = (size_t)(n0 + r) * K + kt + g * 8;
            async16(B + go, &lds[base]);
            if (TERMS == 3) async16(B + bPlane + go, &lds[base + BSZ]);
        }
    };

    stage(0, 0);
    for (int kt = 0; kt < K; kt += 32) {
        const int p = (kt >> 5) & 1;
        __syncthreads();
        if (kt + 32 < K) stage(p ^ 1, kt + 32);
        const u16* L = &lds[p * BUF];
        if (TERMS == 3) {
            f16x8 A0h0[FM], A0h1[FM], B0h0[FN], B0h1[FN];
            f16x8 B1h0[FN], B1h1[FN], A1h0[FM], A1h1[FM];
            RDAF(A0h0, 0, 0) RDBF(B0h0, 0, 0)
            RDAF(A0h1, 0, 1) RDBF(B0h1, 0, 1)
            RDBF(B1h0, 1, 0)
            MMW(A0h0, B0h0)
            RDBF(B1h1, 1, 1)
            MMW(A0h1, B0h1)
            RDAF(A1h0, 1, 0)
            MMW(A0h0, B1h0)
            MMW(A0h1, B1h1)
            RDAF(A1h1, 1, 1)
            MMW(A1h0, B0h0)
            MMW(A1h1, B0h1)
        } else {
            bf16x8 Ah0[FM], Ah1[FM], Bh0[FN], Bh1[FN];
            #pragma unroll
            for (int f = 0; f < FM; ++f)
                Ah0[f] = *(const bf16x8*)&L[arow[f] * 32 + (half ^ asw[f]) * 8];
            #pragma unroll
            for (int f = 0; f < FN; ++f)
                Bh0[f] = *(const bf16x8*)&L[ASZ + brow[f] * 32 + (half ^ bsw[f]) * 8];
            #pragma unroll
            for (int f = 0; f < FM; ++f)
                Ah1[f] = *(const bf16x8*)&L[arow[f] * 32 + ((2 + half) ^ asw[f]) * 8];
            #pragma unroll
            for (int f = 0; f < FN; ++f)
                Bh1[f] = *(const bf16x8*)&L[ASZ + brow[f] * 32 + ((2 + half) ^ bsw[f]) * 8];
            MMWB(Ah0, Bh0)
            MMWB(Ah1, Bh1)
        }
    }

    #pragma unroll
    for (int i = 0; i < FM; ++i) {
        #pragma unroll
        for (int j = 0; j < FN; ++j) {
            int col = n0 + rn + j * 32 + l31;
            #pragma unroll
            for (int r = 0; r < 16; ++r) {
                int row = m0 + rm + i * 32 + (r & 3) + 8 * (r >> 2) + 4 * half;
                float v = acc[i][j][r];
                size_t o = (size_t)row * N + col;
                if (EPI == 0) {
                    ((float*)Cb + blockIdx.z * cBatch)[o] = v;
                } else if (EPI == 1) {
                    u16* C0 = (u16*)Cb + blockIdx.z * cBatch;
                    float vs = v * 0.000244140625f;
                    _Float16 h0 = (_Float16)vs;
                    _Float16 h1 = (_Float16)(vs - (float)h0);
                    C0[o] = __builtin_bit_cast(u16, h0);
                    C0[cPlane + o] = __builtin_bit_cast(u16, h1);
                } else {
                    ((u16*)Cb + blockIdx.z * cBatch)[o] = f2bf(v);
                }
            }
        }
    }
}

// ---------------- fat-wave 3-term split GEMM: 256x256 tile, 4 waves, FM=FN=4 ----------
// LDS-BW-bound fix: wave tile 128x128 doubles MFMA per LDS byte read.
// reads/K-tile/CU: 4 waves x 32KB = 128KB (vs 192KB at FM4/FN2) + 64KB writes
// -> LDS wall ~1500cyc vs MFMA 768. acc=256 VGPR -> 1 wave/SIMD (256thr,
// launch_bounds(256,1), ~400+ VGPR). All latency hidden in-wave by the
// pipelined read order; LDS port is the throughput limit, not latency.
template<int EPI>
__global__ __launch_bounds__(256, 1)
void gemm_s5(const u16* __restrict__ Ab, size_t aBatch, size_t aPlane,
             const u16* __restrict__ Bb, size_t bBatch, size_t bPlane,
             void* __restrict__ Cb, size_t cBatch, size_t cPlane,
             int M, int N, int K)
{
    constexpr int TM = 256, TN = 256;
    constexpr int ASZ = TM * 32;           // 8192 el
    constexpr int BSZ = TN * 32;           // 8192 el
    constexpr int BUF = 2 * (ASZ + BSZ);   // A0|A1|B0|B1 = 32768 el = 64 KB
    constexpr int FM = 4, FN = 4;
    extern __shared__ __align__(16) u16 lds[];   // 2*BUF = 128 KB

    // XCD cluster swizzle (grid 8x8)
    int bid = blockIdx.x + gridDim.x * blockIdx.y;
    int cpr = gridDim.x >> 2;
    int c8 = bid & 7, kk = bid >> 3;
    int bx = (kk % cpr) * 4 + (c8 & 3);
    int by = (kk / cpr) * 2 + (c8 >> 2);

    const u16* A = Ab + blockIdx.z * aBatch;
    const u16* B = Bb + blockIdx.z * bBatch;
    const int tid = threadIdx.x;
    const int lane = tid & 63, wave = tid >> 6;
    const int m0 = by * TM, n0 = bx * TN;
    const int l31 = lane & 31, half = lane >> 5;
    const int rm = (wave >> 1) * 128;      // 2x2 wave grid, 128x128 per wave
    const int rn = (wave & 1) * 128;

    int arow[FM], asw[FM], brow[FN], bsw[FN];
    #pragma unroll
    for (int f = 0; f < FM; ++f) { arow[f] = rm + f * 32 + l31; asw[f] = (arow[f] >> 1) & 3; }
    #pragma unroll
    for (int f = 0; f < FN; ++f) { brow[f] = rn + f * 32 + l31; bsw[f] = (brow[f] >> 1) & 3; }

    f32x16 acc[FM][FN];
    #pragma unroll
    for (int i = 0; i < FM; ++i)
        #pragma unroll
        for (int j = 0; j < FN; ++j)
            #pragma unroll
            for (int r = 0; r < 16; ++r) acc[i][j][r] = 0.f;

    auto stage = [&](int pp, int kt) {
        #pragma unroll
        for (int it = 0; it < 4; ++it) {           // A: 256 rows, 4 thr/row
            int s = tid + it * 256;
            int r = s >> 2;
            int g = (s & 3) ^ ((r >> 1) & 3);
            int base = pp * BUF + (it * 256 + wave * 64) * 8;
            size_t go = (size_t)(m0 + r) * K + kt + g * 8;
            async16(A + go, &lds[base]);
            async16(A + aPlane + go, &lds[base + ASZ]);
        }
        #pragma unroll
        for (int it = 0; it < 4; ++it) {           // B: 256 rows
            int s = tid + it * 256;
            int r = s >> 2;
            int g = (s & 3) ^ ((r >> 1) & 3);
            int base = pp * BUF + 2 * ASZ + (it * 256 + wave * 64) * 8;
            size_t go = (size_t)(n0 + r) * K + kt + g * 8;
            async16(B + go, &lds[base]);
            async16(B + bPlane + go, &lds[base + BSZ]);
        }
    };

    stage(0, 0);
    for (int kt = 0; kt < K; kt += 32) {
        const int p = (kt >> 5) & 1;
        __syncthreads();
        if (kt + 32 < K) stage(p ^ 1, kt + 32);
        const u16* L = &lds[p * BUF];
        // register-pipelined 6 groups (t1h0,t1h1,t2h0,t2h1,t3h0,t3h1)
        f16x8 A0h0[FM], A0h1[FM], B0h0[FN], B0h1[FN];
        f16x8 B1h0[FN], B1h1[FN], A1h0[FM], A1h1[FM];
        RDAF(A0h0, 0, 0) RDBF(B0h0, 0, 0)
        RDAF(A0h1, 0, 1) RDBF(B0h1, 0, 1)
        RDBF(B1h0, 1, 0)
        MMW(A0h0, B0h0)
        RDBF(B1h1, 1, 1)
        MMW(A0h1, B0h1)
        RDAF(A1h0, 1, 0)
        MMW(A0h0, B1h0)
        MMW(A0h1, B1h1)
        RDAF(A1h1, 1, 1)
        MMW(A1h0, B0h0)
        MMW(A1h1, B0h1)
    }

    #pragma unroll
    for (int i = 0; i < FM; ++i) {
        #pragma unroll
        for (int j = 0; j < FN; ++j) {
            int col = n0 + rn + j * 32 + l31;
            #pragma unroll
            for (int r = 0; r < 16; ++r) {
                int row = m0 + rm + i * 32 + (r & 3) + 8 * (r >> 2) + 4 * half;
                float v = acc[i][j][r];
                size_t o = (size_t)row * N + col;
                if (EPI == 0) {
                    ((float*)Cb + blockIdx.z * cBatch)[o] = v;
                } else if (EPI == 1) {
                    u16* C0 = (u16*)Cb + blockIdx.z * cBatch;
                    float vs = v * 0.000244140625f;
                    _Float16 h0 = (_Float16)vs;
                    _Float16 h1 = (_Float16)(vs - (float)h0);
                    C0[o] = __builtin_bit_cast(u16, h0);
                    C0[cPlane + o] = __builtin_bit_cast(u16, h1);
                } else {
                    ((u16*)Cb + blockIdx.z * cBatch)[o] = f2bf(v);
                }
            }
        }
    }
}

#undef RDAF
#undef RDBF
#undef MMW
#undef MMWB

// ---------------- row softmax (2048 cols) -> bf16 ----------------
__global__ __launch_bounds__(256)
void softmax_p(const float* __restrict__ Sb, size_t sBatch, u16* __restrict__ Pb, size_t pBatch)
{
    const float* S = Sb + blockIdx.y * sBatch + (size_t)blockIdx.x * 2048;
    u16* P = Pb + blockIdx.y * pBatch + (size_t)blockIdx.x * 2048;
    const int tid = threadIdx.x;

    float4 v0 = *(const float4*)&S[tid * 4];
    float4 v1 = *(const float4*)&S[1024 + tid * 4];

    float m = fmaxf(fmaxf(fmaxf(v0.x, v0.y), fmaxf(v0.z, v0.w)),
                    fmaxf(fmaxf(v1.x, v1.y), fmaxf(v1.z, v1.w)));
    #pragma unroll
    for (int off = 32; off > 0; off >>= 1)
        m = fmaxf(m, __shfl_xor(m, off, 64));
    __shared__ float redm[4];
    if ((tid & 63) == 0) redm[tid >> 6] = m;
    __syncthreads();
    m = fmaxf(fmaxf(redm[0], redm[1]), fmaxf(redm[2], redm[3]));

    v0.x = __expf(v0.x - m); v0.y = __expf(v0.y - m);
    v0.z = __expf(v0.z - m); v0.w = __expf(v0.w - m);
    v1.x = __expf(v1.x - m); v1.y = __expf(v1.y - m);
    v1.z = __expf(v1.z - m); v1.w = __expf(v1.w - m);

    float s = v0.x + v0.y + v0.z + v0.w + v1.x + v1.y + v1.z + v1.w;
    #pragma unroll
    for (int off = 32; off > 0; off >>= 1)
        s += __shfl_xor(s, off, 64);
    __shared__ float reds[4];
    if ((tid & 63) == 0) reds[tid >> 6] = s;
    __syncthreads();
    s = reds[0] + reds[1] + reds[2] + reds[3];

    const float r = 1.0f / s;
    ushort4 o0 = { f2bf(v0.x * r), f2bf(v0.y * r), f2bf(v0.z * r), f2bf(v0.w * r) };
    ushort4 o1 = { f2bf(v1.x * r), f2bf(v1.y * r), f2bf(v1.z * r), f2bf(v1.w * r) };
    *(ushort4*)&P[tid * 4] = o0;
    *(ushort4*)&P[1024 + tid * 4] = o1;
}

// ---------------- driver ----------------
extern "C" void kernel_launch(void* const* d_in, const int* in_sizes, int n_in,
                              void* d_out, int out_size, void* d_ws, size_t ws_size,
                              hipStream_t stream)
{
    const size_t MB = 1048576;
    const size_t WREG = 34 * MB;
    const size_t PER  = 32 * MB;
    const size_t PER_US = PER / 2, PER_F = PER / 4;

    char* ws = (char*)d_ws;
    u16* WQT2 = (u16*)ws;
    u16* WKT2 = (u16*)(ws + 4 * MB);
    u16* M2   = (u16*)(ws + 8 * MB);
    u16* WObf = (u16*)(ws + 12 * MB);
    u16* WVT  = (u16*)(ws + 14 * MB);
    u16* WOV  = (u16*)(ws + 16 * MB);
    u16* xbf  = (u16*)(ws + 18 * MB);

    int G = (ws_size >= WREG + 4 * PER) ? 4 : (ws_size >= WREG + 2 * PER) ? 2 : 1;

    const float* x = (const float*)d_in[0];
    float* out = (float*)d_out;
    dim3 blk(256);

    hipFuncSetAttribute((const void*)gemm_s5<0>,
                        hipFuncAttributeMaxDynamicSharedMemorySize, 131072);
    hipFuncSetAttribute((const void*)gemm_w<3, 1, 256, 128, 4, 2>,
                        hipFuncAttributeMaxDynamicSharedMemorySize, 98304);

    // ---- weight prep (once) ----
    tsplit_h2<<<dim3(32, 32, 1), blk, 0, stream>>>((const float*)d_in[1], 0, WQT2, 0, 1048576, 1024, 1024);
    tsplit_h2<<<dim3(32, 32, 1), blk, 0, stream>>>((const float*)d_in[2], 0, WKT2, 0, 1048576, 1024, 1024);
    gemm_big<3, 1><<<dim3(8, 8, 1), blk, 0, stream>>>(WKT2, 0, 1048576, WQT2, 0, 1048576,
                                                      M2, 0, 1048576, 1024, 1024, 1024);
    wcast<<<1024, blk, 0, stream>>>((const float4*)d_in[4], WObf);
    tcast<<<dim3(32, 32, 1), blk, 0, stream>>>((const float*)d_in[3], WVT, 1024, 1024);
    gemm_big<1, 2><<<dim3(8, 8, 1), blk, 0, stream>>>(WObf, 0, 0, WVT, 0, 0,
                                                      WOV, 0, 0, 1024, 1024, 1024);

    for (int b0 = 0; b0 < 4; b0 += G) {
        char* R = ws + WREG;
        u16*   xT2 = (u16*)R;               // [i,d] 64x f16-split, plane 2097152 u16
        u16*   TT2 = (u16*)(R + 8 * MB);    // [j,d] split(T/64)
        float* S32 = (float*)(R + 16 * MB); // fp32 [i,j]
        u16*   Pb  = (u16*)R;               // bf16 [i,j] (over dead xT2)
        u16*   PTb = (u16*)(R + 8 * MB);    // bf16 [j,i] (over dead TT2)
        u16*   XPT = (u16*)(R + 16 * MB);   // bf16 [j,d'] (over dead S32)

        // x -> xbf (bf16 copy) + xT2 (transposed 64x f16 2-plane), one pass
        xprep<<<dim3(64, 32, G), blk, 0, stream>>>(x + (size_t)b0 * 2097152, 2097152,
                                                   xbf + (size_t)b0 * 2097152, 2097152,
                                                   xT2, PER_US, 2097152);
        // T^T = (64x)^T M: [j,d] f16-split out
        gemm_w<3, 1, 256, 128, 4, 2><<<dim3(8, 8, G), 512, 98304, stream>>>(
            xT2, PER_US, 2097152, M2, 0, 1048576, TT2, PER_US, 2097152, 2048, 1024, 1024);
        // S[i,j] = (64x)[i,:] . (T/64)[j,:]  (256^2 tiles -> grid 8x8)
        gemm_s5<0><<<dim3(8, 8, G), blk, 131072, stream>>>(
            xT2, PER_US, 2097152, TT2, PER_US, 2097152, S32, PER_F, 0, 2048, 2048, 1024);
        softmax_p<<<dim3(2048, G), blk, 0, stream>>>(S32, PER_F, Pb, PER_US);
        tbf16<<<dim3(64, 64, G), blk, 0, stream>>>(Pb, PER_US, PTb, PER_US);
        // XPT[j,d'] = PT[j,:] . xbf[d',:]
        gemm_w<1, 2, 256, 128, 4, 2><<<dim3(8, 8, G), 512, 49152, stream>>>(
            PTb, PER_US, 0, xbf + (size_t)b0 * 2097152, 2097152, 0,
            XPT, PER_US, 0, 2048, 1024, 2048);
        // out[d,j] = WOV[d,:] . XPT[j,:]
        gemm_w<1, 0, 256, 128, 4, 2><<<dim3(16, 4, G), 512, 49152, stream>>>(
            WOV, 0, 0, XPT, PER_US, 0, out + (size_t)b0 * 2097152, 2097152, 0,
            1024, 2048, 1024);
    }
}

// Round 7
// 393.455 us; speedup vs baseline: 1.1014x; 1.0483x over previous
//
#include <hip/hip_runtime.h>
#include <cstddef>
#include <cstdint>

typedef unsigned short u16;
typedef __attribute__((ext_vector_type(8))) short bf16x8;
typedef __attribute__((ext_vector_type(8))) _Float16 f16x8;
typedef __attribute__((ext_vector_type(4))) float f32x4;
typedef __attribute__((ext_vector_type(16))) float f32x16;

#define GLOBAL_AS __attribute__((address_space(1)))
#define LDS_AS __attribute__((address_space(3)))

__device__ __forceinline__ void async16(const u16* g, u16* l) {
    __builtin_amdgcn_global_load_lds((GLOBAL_AS const uint32_t*)g,
                                     (LDS_AS uint32_t*)l, 16, 0, 0);
}

__device__ __forceinline__ u16 f2bf(float f) {
    uint32_t u = __builtin_bit_cast(uint32_t, f);
    uint32_t r = (u + 0x7FFFu + ((u >> 16) & 1u)) >> 16;
    return (u16)r;
}

// ---------------- fused weight prep (one kernel, 4 roles by blockIdx.z) ------------
// role 0: W_Q -> transpose + f16 2-split x64   role 1: W_K -> same
// role 2: W_V -> transpose + bf16 cast          role 3: W_O -> bf16 cast (no transpose)
__global__ __launch_bounds__(256)
void wprep(const float* __restrict__ WQ, const float* __restrict__ WK,
           const float* __restrict__ WV, const float* __restrict__ WO,
           u16* __restrict__ DQ, u16* __restrict__ DK,
           u16* __restrict__ DV, u16* __restrict__ DOb)
{
    const int role = blockIdx.z;
    __shared__ float t[32][33];
    int tx = threadIdx.x & 31, ty = threadIdx.x >> 5;
    int c0 = blockIdx.x * 32, r0 = blockIdx.y * 32;
    const float* S = role == 0 ? WQ : role == 1 ? WK : role == 2 ? WV : WO;

    if (role == 3) {
        #pragma unroll
        for (int k = 0; k < 4; ++k) {
            size_t o = (size_t)(r0 + ty + 8 * k) * 1024 + c0 + tx;
            DOb[o] = f2bf(S[o]);
        }
        return;
    }
    #pragma unroll
    for (int k = 0; k < 4; ++k)
        t[ty + 8 * k][tx] = S[(size_t)(r0 + ty + 8 * k) * 1024 + c0 + tx];
    __syncthreads();
    if (role == 2) {
        #pragma unroll
        for (int k = 0; k < 4; ++k)
            DV[(size_t)(c0 + ty + 8 * k) * 1024 + r0 + tx] = f2bf(t[tx][ty + 8 * k]);
    } else {
        u16* D = role == 0 ? DQ : DK;
        #pragma unroll
        for (int k = 0; k < 4; ++k) {
            float a = t[tx][ty + 8 * k] * 64.0f;
            _Float16 h0 = (_Float16)a;
            _Float16 h1 = (_Float16)(a - (float)h0);
            size_t o = (size_t)(c0 + ty + 8 * k) * 1024 + r0 + tx;
            D[o] = __builtin_bit_cast(u16, h0);
            D[1048576 + o] = __builtin_bit_cast(u16, h1);
        }
    }
}

// fused x-prep: fp32 x [1024, 2048] -> bf16 copy [1024,2048] AND transposed
// f16 2-plane x64 split [2048, 1024]
__global__ __launch_bounds__(256)
void xprep(const float* __restrict__ Sb, size_t sBatch,
           u16* __restrict__ BFb, size_t bfBatch,
           u16* __restrict__ Db, size_t dBatch, size_t plane)
{
    const float* S = Sb + blockIdx.z * sBatch;
    u16* BF = BFb + blockIdx.z * bfBatch;
    u16* D = Db + blockIdx.z * dBatch;
    __shared__ float t[32][33];
    int tx = threadIdx.x & 31, ty = threadIdx.x >> 5;
    int c0 = blockIdx.x * 32, r0 = blockIdx.y * 32;
    #pragma unroll
    for (int k = 0; k < 4; ++k) {
        float v = S[(size_t)(r0 + ty + 8 * k) * 2048 + c0 + tx];
        t[ty + 8 * k][tx] = v;
        BF[(size_t)(r0 + ty + 8 * k) * 2048 + c0 + tx] = f2bf(v);
    }
    __syncthreads();
    #pragma unroll
    for (int k = 0; k < 4; ++k) {
        float a = t[tx][ty + 8 * k] * 64.0f;
        _Float16 h0 = (_Float16)a;
        _Float16 h1 = (_Float16)(a - (float)h0);
        size_t o = (size_t)(c0 + ty + 8 * k) * 1024 + r0 + tx;
        D[o] = __builtin_bit_cast(u16, h0);
        D[plane + o] = __builtin_bit_cast(u16, h1);
    }
}

// bf16 [2048,2048] transpose
__global__ __launch_bounds__(256)
void tbf16(const u16* __restrict__ Sb, size_t sBatch, u16* __restrict__ Db, size_t dBatch)
{
    const u16* S = Sb + blockIdx.z * sBatch;
    u16* D = Db + blockIdx.z * dBatch;
    __shared__ u16 t[32][34];
    int tx = threadIdx.x & 31, ty = threadIdx.x >> 5;
    int c0 = blockIdx.x * 32, r0 = blockIdx.y * 32;
    #pragma unroll
    for (int k = 0; k < 4; ++k)
        t[ty + 8 * k][tx] = S[(size_t)(r0 + ty + 8 * k) * 2048 + c0 + tx];
    __syncthreads();
    #pragma unroll
    for (int k = 0; k < 4; ++k)
        D[(size_t)(c0 + ty + 8 * k) * 2048 + r0 + tx] = t[tx][ty + 8 * k];
}

// ---------------- 128-tile 16x16 MFMA GEMM (weight prep, split-K over z) ----------
#define MMF4(AF, BF)                                                                   \
    _Pragma("unroll") for (int i = 0; i < 4; ++i)                                      \
        _Pragma("unroll") for (int j = 0; j < 4; ++j)                                  \
            acc[i][j] = __builtin_amdgcn_mfma_f32_16x16x32_f16(AF[i], BF[j], acc[i][j], 0, 0, 0);
#define MMB4(AF, BF)                                                                   \
    _Pragma("unroll") for (int i = 0; i < 4; ++i)                                      \
        _Pragma("unroll") for (int j = 0; j < 4; ++j)                                  \
            acc[i][j] = __builtin_amdgcn_mfma_f32_16x16x32_bf16(AF[i], BF[j], acc[i][j], 0, 0, 0);

// SPLITK=1: blockIdx.z selects a K/4 slice; fp32 partial written to Cb + z*cBatch.
template<int TERMS, int SPLITK>
__global__ __launch_bounds__(256)
void gemm_big(const u16* __restrict__ Ab, size_t aPlane,
              const u16* __restrict__ Bb, size_t bPlane,
              float* __restrict__ Cb, size_t cBatch,
              int M, int N, int K)
{
    constexpr int RSZ = 4096;
    constexpr int BUF = (TERMS == 3 ? 4 : 2) * RSZ;
    __shared__ u16 lds[2 * BUF];
    const u16* A = Ab;
    const u16* B = Bb;
    const int z = blockIdx.z;
    const int kt0 = SPLITK ? z * (K >> 2) : 0;
    const int kend = SPLITK ? kt0 + (K >> 2) : K;
    const int tid = threadIdx.x;
    const int lane = tid & 63, wave = tid >> 6;
    const int m0 = blockIdx.y * 128, n0 = blockIdx.x * 128;
    const int l15 = lane & 15, q = lane >> 4;
    const int rm = (wave >> 1) * 64, rn = (wave & 1) * 64;

    int sr[2], sg[2], sbase[2];
    #pragma unroll
    for (int it = 0; it < 2; ++it) {
        int s = tid + it * 256;
        sr[it] = s >> 2;
        sg[it] = (s & 3) ^ ((sr[it] >> 1) & 3);
        sbase[it] = (it * 256 + wave * 64) * 8;
    }
    const int fsw = (q ^ ((l15 >> 1) & 3)) * 8;
    int aoff[4], boff[4];
    #pragma unroll
    for (int f = 0; f < 4; ++f) {
        aoff[f] = (rm + f * 16 + l15) * 32 + fsw;
        boff[f] = (rn + f * 16 + l15) * 32 + fsw;
    }

    f32x4 acc[4][4];
    #pragma unroll
    for (int i = 0; i < 4; ++i)
        #pragma unroll
        for (int j = 0; j < 4; ++j)
            acc[i][j] = (f32x4){0.f, 0.f, 0.f, 0.f};

#define STAGEB(PP, KT)                                                                 \
    do {                                                                               \
        _Pragma("unroll")                                                              \
        for (int it = 0; it < 2; ++it) {                                               \
            const size_t ao = (size_t)(m0 + sr[it]) * K + (KT) + sg[it] * 8;           \
            const size_t bo = (size_t)(n0 + sr[it]) * K + (KT) + sg[it] * 8;           \
            const int d = (PP) * BUF + sbase[it];                                      \
            if (TERMS == 3) {                                                          \
                async16(A + ao, &lds[d]);                                              \
                async16(A + aPlane + ao, &lds[d + RSZ]);                               \
                async16(B + bo, &lds[d + 2 * RSZ]);                                    \
                async16(B + bPlane + bo, &lds[d + 3 * RSZ]);                           \
            } else {                                                                   \
                async16(A + ao, &lds[d]);                                              \
                async16(B + bo, &lds[d + RSZ]);                                        \
            }                                                                          \
        }                                                                              \
    } while (0)

    STAGEB(0, kt0);
    for (int kt = kt0; kt < kend; kt += 32) {
        const int p = (kt >> 5) & 1;
        __syncthreads();
        if (kt + 32 < kend) STAGEB(p ^ 1, kt + 32);
        const u16* L = &lds[p * BUF];
        if (TERMS == 3) {
            f16x8 a0f[4], b0f[4], xf[4];
            #pragma unroll
            for (int f = 0; f < 4; ++f) a0f[f] = *(const f16x8*)&L[aoff[f]];
            #pragma unroll
            for (int f = 0; f < 4; ++f) b0f[f] = *(const f16x8*)&L[2 * RSZ + boff[f]];
            MMF4(a0f, b0f);
            #pragma unroll
            for (int f = 0; f < 4; ++f) xf[f] = *(const f16x8*)&L[3 * RSZ + boff[f]];
            MMF4(a0f, xf);
            #pragma unroll
            for (int f = 0; f < 4; ++f) xf[f] = *(const f16x8*)&L[RSZ + aoff[f]];
            MMF4(xf, b0f);
        } else {
            bf16x8 af[4], bf_[4];
            #pragma unroll
            for (int f = 0; f < 4; ++f) af[f] = *(const bf16x8*)&L[aoff[f]];
            #pragma unroll
            for (int f = 0; f < 4; ++f) bf_[f] = *(const bf16x8*)&L[RSZ + boff[f]];
            MMB4(af, bf_);
        }
    }
#undef STAGEB

    float* C = Cb + (size_t)z * cBatch;
    #pragma unroll
    for (int i = 0; i < 4; ++i) {
        int row = m0 + rm + i * 16 + q * 4;
        #pragma unroll
        for (int j = 0; j < 4; ++j) {
            int col = n0 + rn + j * 16 + l15;
            #pragma unroll
            for (int r = 0; r < 4; ++r)
                C[(size_t)(row + r) * N + col] = acc[i][j][r];
        }
    }
}

// sum 4 fp32 partial planes (1024x1024 each) + epilogue. EPI 1: f16-2split*2^-12; 2: bf16.
template<int EPI>
__global__ __launch_bounds__(256)
void reduce4(const float4* __restrict__ P, u16* __restrict__ D, size_t plane)
{
    size_t i = blockIdx.x * 256 + threadIdx.x;           // float4 index, 262144 total
    float4 a = P[i], b = P[262144 + i], c = P[524288 + i], d = P[786432 + i];
    float v[4] = { a.x + b.x + c.x + d.x, a.y + b.y + c.y + d.y,
                   a.z + b.z + c.z + d.z, a.w + b.w + c.w + d.w };
    if (EPI == 1) {
        #pragma unroll
        for (int k = 0; k < 4; ++k) {
            float vs = v[k] * 0.000244140625f;
            _Float16 h0 = (_Float16)vs;
            _Float16 h1 = (_Float16)(vs - (float)h0);
            D[i * 4 + k] = __builtin_bit_cast(u16, h0);
            D[plane + i * 4 + k] = __builtin_bit_cast(u16, h1);
        }
    } else {
        ushort4 o = { f2bf(v[0]), f2bf(v[1]), f2bf(v[2]), f2bf(v[3]) };
        *(ushort4*)&D[i * 4] = o;
    }
}

// shared fragment-read / MFMA macros for the split GEMM (LDS layout: A0|A1|B0|B1)
#define RDAF(dst, PL, H)                                                               \
    _Pragma("unroll")                                                                  \
    for (int f = 0; f < FM; ++f)                                                       \
        dst[f] = *(const f16x8*)&L[(PL) * ASZ + arow[f] * 32 + ((2 * (H) + half) ^ asw[f]) * 8];
#define RDBF(dst, PL, H)                                                               \
    _Pragma("unroll")                                                                  \
    for (int f = 0; f < FN; ++f)                                                       \
        dst[f] = *(const f16x8*)&L[2 * ASZ + (PL) * BSZ + brow[f] * 32 + ((2 * (H) + half) ^ bsw[f]) * 8];
#define MMW(AF, BF)                                                                    \
    _Pragma("unroll")                                                                  \
    for (int i = 0; i < FM; ++i)                                                       \
        _Pragma("unroll")                                                              \
        for (int j = 0; j < FN; ++j)                                                   \
            acc[i][j] = __builtin_amdgcn_mfma_f32_32x32x16_f16(AF[i], BF[j], acc[i][j], 0, 0, 0);
#define MMWB(AF, BF)                                                                   \
    _Pragma("unroll")                                                                  \
    for (int i = 0; i < FM; ++i)                                                       \
        _Pragma("unroll")                                                              \
        for (int j = 0; j < FN; ++j)                                                   \
            acc[i][j] = __builtin_amdgcn_mfma_f32_32x32x16_bf16(AF[i], BF[j], acc[i][j], 0, 0, 0);

// ---------------- wide-tile 32x32x16 MFMA GEMM (512 thr, dyn LDS, dbuf) ----------------
// TERMS=3: f16 2-plane split, 3 terms (register-pipelined). TERMS=1: bf16.
// EPI: 0 fp32, 1 f16-2split*2^-12, 2 bf16.
template<int TERMS, int EPI, int TM, int TN, int WGM, int WGN>
__global__ __launch_bounds__(512, 2)
void gemm_w(const u16* __restrict__ Ab, size_t aBatch, size_t aPlane,
            const u16* __restrict__ Bb, size_t bBatch, size_t bPlane,
            void* __restrict__ Cb, size_t cBatch, size_t cPlane,
            int M, int N, int K)
{
    constexpr int ASZ = TM * 32;
    constexpr int BSZ = TN * 32;
    constexpr int APL = (TERMS == 3) ? 2 : 1;
    constexpr int BUF = APL * (ASZ + BSZ);
    constexpr int FM = TM / WGM / 32;
    constexpr int FN = TN / WGN / 32;
    constexpr int AIT = TM / 128;
    constexpr int BIT = TN / 128;
    extern __shared__ __align__(16) u16 lds[];

    int bid = blockIdx.x + gridDim.x * blockIdx.y;
    int cpr = gridDim.x >> 2;
    int c8 = bid & 7, kk = bid >> 3;
    int bx = (kk % cpr) * 4 + (c8 & 3);
    int by = (kk / cpr) * 2 + (c8 >> 2);

    const u16* A = Ab + blockIdx.z * aBatch;
    const u16* B = Bb + blockIdx.z * bBatch;
    const int tid = threadIdx.x;
    const int lane = tid & 63, wave = tid >> 6;
    const int m0 = by * TM, n0 = bx * TN;
    const int l31 = lane & 31, half = lane >> 5;
    const int rm = (wave / WGN) * (TM / WGM);
    const int rn = (wave % WGN) * (TN / WGN);

    int arow[FM], asw[FM], brow[FN], bsw[FN];
    #pragma unroll
    for (int f = 0; f < FM; ++f) { arow[f] = rm + f * 32 + l31; asw[f] = (arow[f] >> 1) & 3; }
    #pragma unroll
    for (int f = 0; f < FN; ++f) { brow[f] = rn + f * 32 + l31; bsw[f] = (brow[f] >> 1) & 3; }

    f32x16 acc[FM][FN];
    #pragma unroll
    for (int i = 0; i < FM; ++i)
        #pragma unroll
        for (int j = 0; j < FN; ++j)
            #pragma unroll
            for (int r = 0; r < 16; ++r) acc[i][j][r] = 0.f;

    auto stage = [&](int pp, int kt) {
        #pragma unroll
        for (int it = 0; it < AIT; ++it) {
            int s = tid + it * 512;
            int r = s >> 2;
            int g = (s & 3) ^ ((r >> 1) & 3);
            int base = pp * BUF + (it * 512 + wave * 64) * 8;
            size_t go = (size_t)(m0 + r) * K + kt + g * 8;
            async16(A + go, &lds[base]);
            if (TERMS == 3) async16(A + aPlane + go, &lds[base + ASZ]);
        }
        #pragma unroll
        for (int it = 0; it < BIT; ++it) {
            int s = tid + it * 512;
            int r = s >> 2;
            int g = (s & 3) ^ ((r >> 1) & 3);
            int base = pp * BUF + APL * ASZ + (it * 512 + wave * 64) * 8;
            size_t go = (size_t)(n0 + r) * K + kt + g * 8;
            async16(B + go, &lds[base]);
            if (TERMS == 3) async16(B + bPlane + go, &lds[base + BSZ]);
        }
    };

    stage(0, 0);
    for (int kt = 0; kt < K; kt += 32) {
        const int p = (kt >> 5) & 1;
        __syncthreads();
        if (kt + 32 < K) stage(p ^ 1, kt + 32);
        const u16* L = &lds[p * BUF];
        if (TERMS == 3) {
            f16x8 A0h0[FM], A0h1[FM], B0h0[FN], B0h1[FN];
            f16x8 B1h0[FN], B1h1[FN], A1h0[FM], A1h1[FM];
            RDAF(A0h0, 0, 0) RDBF(B0h0, 0, 0)
            RDAF(A0h1, 0, 1) RDBF(B0h1, 0, 1)
            RDBF(B1h0, 1, 0)
            MMW(A0h0, B0h0)
            RDBF(B1h1, 1, 1)
            MMW(A0h1, B0h1)
            RDAF(A1h0, 1, 0)
            MMW(A0h0, B1h0)
            MMW(A0h1, B1h1)
            RDAF(A1h1, 1, 1)
            MMW(A1h0, B0h0)
            MMW(A1h1, B0h1)
        } else {
            bf16x8 Ah0[FM], Ah1[FM], Bh0[FN], Bh1[FN];
            #pragma unroll
            for (int f = 0; f < FM; ++f)
                Ah0[f] = *(const bf16x8*)&L[arow[f] * 32 + (half ^ asw[f]) * 8];
            #pragma unroll
            for (int f = 0; f < FN; ++f)
                Bh0[f] = *(const bf16x8*)&L[ASZ + brow[f] * 32 + (half ^ bsw[f]) * 8];
            #pragma unroll
            for (int f = 0; f < FM; ++f)
                Ah1[f] = *(const bf16x8*)&L[arow[f] * 32 + ((2 + half) ^ asw[f]) * 8];
            #pragma unroll
            for (int f = 0; f < FN; ++f)
                Bh1[f] = *(const bf16x8*)&L[ASZ + brow[f] * 32 + ((2 + half) ^ bsw[f]) * 8];
            MMWB(Ah0, Bh0)
            MMWB(Ah1, Bh1)
        }
    }

    #pragma unroll
    for (int i = 0; i < FM; ++i) {
        #pragma unroll
        for (int j = 0; j < FN; ++j) {
            int col = n0 + rn + j * 32 + l31;
            #pragma unroll
            for (int r = 0; r < 16; ++r) {
                int row = m0 + rm + i * 32 + (r & 3) + 8 * (r >> 2) + 4 * half;
                float v = acc[i][j][r];
                size_t o = (size_t)row * N + col;
                if (EPI == 0) {
                    ((float*)Cb + blockIdx.z * cBatch)[o] = v;
                } else if (EPI == 1) {
                    u16* C0 = (u16*)Cb + blockIdx.z * cBatch;
                    float vs = v * 0.000244140625f;
                    _Float16 h0 = (_Float16)vs;
                    _Float16 h1 = (_Float16)(vs - (float)h0);
                    C0[o] = __builtin_bit_cast(u16, h0);
                    C0[cPlane + o] = __builtin_bit_cast(u16, h1);
                } else {
                    ((u16*)Cb + blockIdx.z * cBatch)[o] = f2bf(v);
                }
            }
        }
    }
}

#undef RDAF
#undef RDBF
#undef MMW
#undef MMWB

// ---------------- row softmax (2048 cols) -> bf16 ----------------
__global__ __launch_bounds__(256)
void softmax_p(const float* __restrict__ Sb, size_t sBatch, u16* __restrict__ Pb, size_t pBatch)
{
    const float* S = Sb + blockIdx.y * sBatch + (size_t)blockIdx.x * 2048;
    u16* P = Pb + blockIdx.y * pBatch + (size_t)blockIdx.x * 2048;
    const int tid = threadIdx.x;

    float4 v0 = *(const float4*)&S[tid * 4];
    float4 v1 = *(const float4*)&S[1024 + tid * 4];

    float m = fmaxf(fmaxf(fmaxf(v0.x, v0.y), fmaxf(v0.z, v0.w)),
                    fmaxf(fmaxf(v1.x, v1.y), fmaxf(v1.z, v1.w)));
    #pragma unroll
    for (int off = 32; off > 0; off >>= 1)
        m = fmaxf(m, __shfl_xor(m, off, 64));
    __shared__ float redm[4];
    if ((tid & 63) == 0) redm[tid >> 6] = m;
    __syncthreads();
    m = fmaxf(fmaxf(redm[0], redm[1]), fmaxf(redm[2], redm[3]));

    v0.x = __expf(v0.x - m); v0.y = __expf(v0.y - m);
    v0.z = __expf(v0.z - m); v0.w = __expf(v0.w - m);
    v1.x = __expf(v1.x - m); v1.y = __expf(v1.y - m);
    v1.z = __expf(v1.z - m); v1.w = __expf(v1.w - m);

    float s = v0.x + v0.y + v0.z + v0.w + v1.x + v1.y + v1.z + v1.w;
    #pragma unroll
    for (int off = 32; off > 0; off >>= 1)
        s += __shfl_xor(s, off, 64);
    __shared__ float reds[4];
    if ((tid & 63) == 0) reds[tid >> 6] = s;
    __syncthreads();
    s = reds[0] + reds[1] + reds[2] + reds[3];

    const float r = 1.0f / s;
    ushort4 o0 = { f2bf(v0.x * r), f2bf(v0.y * r), f2bf(v0.z * r), f2bf(v0.w * r) };
    ushort4 o1 = { f2bf(v1.x * r), f2bf(v1.y * r), f2bf(v1.z * r), f2bf(v1.w * r) };
    *(ushort4*)&P[tid * 4] = o0;
    *(ushort4*)&P[1024 + tid * 4] = o1;
}

// ---------------- driver ----------------
extern "C" void kernel_launch(void* const* d_in, const int* in_sizes, int n_in,
                              void* d_out, int out_size, void* d_ws, size_t ws_size,
                              hipStream_t stream)
{
    const size_t MB = 1048576;
    const size_t WREG = 34 * MB;
    const size_t PER  = 32 * MB;
    const size_t PER_US = PER / 2, PER_F = PER / 4;

    char* ws = (char*)d_ws;
    u16* WQT2 = (u16*)ws;
    u16* WKT2 = (u16*)(ws + 4 * MB);
    u16* M2   = (u16*)(ws + 8 * MB);
    u16* WObf = (u16*)(ws + 12 * MB);
    u16* WVT  = (u16*)(ws + 14 * MB);
    u16* WOV  = (u16*)(ws + 16 * MB);
    u16* xbf  = (u16*)(ws + 18 * MB);

    int G = (ws_size >= WREG + 4 * PER) ? 4 : (ws_size >= WREG + 2 * PER) ? 2 : 1;

    const float* x = (const float*)d_in[0];
    float* out = (float*)d_out;
    dim3 blk(256);

    hipFuncSetAttribute((const void*)gemm_w<3, 0, 256, 256, 2, 4>,
                        hipFuncAttributeMaxDynamicSharedMemorySize, 131072);
    hipFuncSetAttribute((const void*)gemm_w<3, 1, 256, 128, 4, 2>,
                        hipFuncAttributeMaxDynamicSharedMemorySize, 98304);

    // ---- weight prep (once): fused elementwise + split-K GEMMs ----
    float* PART = (float*)(ws + WREG);   // 16 MB fp32 partials; free until xprep
    wprep<<<dim3(32, 32, 4), blk, 0, stream>>>(
        (const float*)d_in[1], (const float*)d_in[2],
        (const float*)d_in[3], (const float*)d_in[4],
        WQT2, WKT2, WVT, WObf);
    gemm_big<3, 1><<<dim3(8, 8, 4), blk, 0, stream>>>(WKT2, 1048576, WQT2, 1048576,
                                                      PART, 1048576, 1024, 1024, 1024);
    reduce4<1><<<1024, blk, 0, stream>>>((const float4*)PART, M2, 1048576);
    gemm_big<1, 1><<<dim3(8, 8, 4), blk, 0, stream>>>(WObf, 0, WVT, 0,
                                                      PART, 1048576, 1024, 1024, 1024);
    reduce4<2><<<1024, blk, 0, stream>>>((const float4*)PART, WOV, 0);

    for (int b0 = 0; b0 < 4; b0 += G) {
        char* R = ws + WREG;
        u16*   xT2 = (u16*)R;               // [i,d] 64x f16-split, plane 2097152 u16
        u16*   TT2 = (u16*)(R + 8 * MB);    // [j,d] split(T/64)
        float* S32 = (float*)(R + 16 * MB); // fp32 [i,j]
        u16*   Pb  = (u16*)R;               // bf16 [i,j] (over dead xT2)
        u16*   PTb = (u16*)(R + 8 * MB);    // bf16 [j,i] (over dead TT2)
        u16*   XPT = (u16*)(R + 16 * MB);   // bf16 [j,d'] (over dead S32)

        // x -> xbf (bf16 copy) + xT2 (transposed 64x f16 2-plane), one pass
        xprep<<<dim3(64, 32, G), blk, 0, stream>>>(x + (size_t)b0 * 2097152, 2097152,
                                                   xbf + (size_t)b0 * 2097152, 2097152,
                                                   xT2, PER_US, 2097152);
        // T^T = (64x)^T M: [j,d] f16-split out
        gemm_w<3, 1, 256, 128, 4, 2><<<dim3(8, 8, G), 512, 98304, stream>>>(
            xT2, PER_US, 2097152, M2, 0, 1048576, TT2, PER_US, 2097152, 2048, 1024, 1024);
        // S[i,j] = (64x)[i,:] . (T/64)[j,:]
        gemm_w<3, 0, 256, 256, 2, 4><<<dim3(8, 8, G), 512, 131072, stream>>>(
            xT2, PER_US, 2097152, TT2, PER_US, 2097152, S32, PER_F, 0, 2048, 2048, 1024);
        softmax_p<<<dim3(2048, G), blk, 0, stream>>>(S32, PER_F, Pb, PER_US);
        tbf16<<<dim3(64, 64, G), blk, 0, stream>>>(Pb, PER_US, PTb, PER_US);
        // XPT[j,d'] = PT[j,:] . xbf[d',:]
        gemm_w<1, 2, 256, 128, 4, 2><<<dim3(8, 8, G), 512, 49152, stream>>>(
            PTb, PER_US, 0, xbf + (size_t)b0 * 2097152, 2097152, 0,
            XPT, PER_US, 0, 2048, 1024, 2048);
        // out[d,j] = WOV[d,:] . XPT[j,:]
        gemm_w<1, 0, 256, 128, 4, 2><<<dim3(16, 4, G), 512, 49152, stream>>>(
            WOV, 0, 0, XPT, PER_US, 0, out + (size_t)b0 * 2097152, 2097152, 0,
            1024, 2048, 1024);
    }
}